// Round 11
// baseline (99.899 us; speedup 1.0000x reference)
//
#include <hip/hip_runtime.h>

typedef __attribute__((ext_vector_type(8))) __bf16 bf16x8;
typedef __attribute__((ext_vector_type(4))) float f32x4;

__device__ __forceinline__ bf16x8 cvt8(f32x4 a, f32x4 b) {
    bf16x8 v;
    v[0] = (__bf16)a.x; v[1] = (__bf16)a.y; v[2] = (__bf16)a.z; v[3] = (__bf16)a.w;
    v[4] = (__bf16)b.x; v[5] = (__bf16)b.y; v[6] = (__bf16)b.z; v[7] = (__bf16)b.w;
    return v;
}

// VALU-pipe cross-lane add via DPP (replaces ds_swizzle-based __shfl_xor)
template <int CTRL>
__device__ __forceinline__ float dpp_addf(float v) {
    union { float f; int i; } s, r;
    s.f = v;
    r.i = __builtin_amdgcn_update_dpp(0, s.i, CTRL, 0xF, 0xF, true);
    return v + r.f;
}

// ---------------------------------------------------------------------------
// Kernel 0: zero 512KB accumulator + build graph offsets from sorted batch.
// ---------------------------------------------------------------------------
__global__ void prep(const int* __restrict__ batch, int nN,
                     float* __restrict__ sums, int* __restrict__ off)
{
    const int i = blockIdx.x * blockDim.x + threadIdx.x;
    const int stride = gridDim.x * blockDim.x;
    for (int t = i; t < 1024 * 128; t += stride) sums[t] = 0.f;
    for (int t = i; t < nN; t += stride) {
        const int b  = batch[t];
        const int bp = (t == 0) ? -1 : batch[t - 1];
        for (int g = bp + 1; g <= b; ++g) off[g] = t;
        if (t == nN - 1) {
            for (int g = b + 1; g <= 1024; ++g) off[g] = nN;
        }
    }
}

// ---------------------------------------------------------------------------
// Kernel 1: 512 thr / 8 waves, 64-row bf16 tiles (2x16KB, XOR-swizzled),
// register-staged with cvt at stage time (two ds_write_b128/thread/tile).
// Phase length (~32 MFMA + softmax) now covers HBM latency, so the counted
// vmcnt at stage_write doesn't stall. Wave w owns cols [16w,16w+16) of both
// states and gates. Softmax reduces on the VALU via DPP. Two lgkm-only
// barriers per tile. Per-graph column sums in registers; atomics only at
// graph boundaries.
// ---------------------------------------------------------------------------
__global__ __launch_bounds__(512, 2) void gnn_main(
    const float* __restrict__ x, const int* __restrict__ batch,
    const float* __restrict__ Wlin, const float* __restrict__ blin,
    const float* __restrict__ Wgate, const float* __restrict__ bgate,
    float* __restrict__ sums, int nN, int P)
{
    __shared__ __bf16 buf[2][64 * 128];   // 2 x 16 KB bf16, 16B-XOR swizzled
    __shared__ float  PS[8][68];          // per-wave row partial sums (padded)
    __shared__ float  invLds[64];         // per-row 1/sum

    const int tid  = threadIdx.x;
    const int lane = tid & 63;
    const int w    = tid >> 6;    // wave 0..7
    const int l15  = lane & 15;
    const int lg   = lane >> 4;   // 0..3

    const int R0 = blockIdx.x * P;
    if (R0 >= nN) return;
    const int R1b = min(R0 + P, nN);
    const int nt  = (R1b - R0 + 63) >> 6;

    // ---- W fragments (B operand): rows [16w,16w+16) of Wlin / Wgate
    bf16x8 bfrag[2][4];
    {
        const float* Wp0 = Wlin  + (size_t)(w * 16 + l15) * 128 + lg * 8;
        const float* Wp1 = Wgate + (size_t)(w * 16 + l15) * 128 + lg * 8;
#pragma unroll
        for (int kk = 0; kk < 4; ++kk) {
            bfrag[0][kk] = cvt8(*(const f32x4*)(Wp0 + kk * 32),
                                *(const f32x4*)(Wp0 + kk * 32 + 4));
            bfrag[1][kk] = cvt8(*(const f32x4*)(Wp1 + kk * 32),
                                *(const f32x4*)(Wp1 + kk * 32 + 4));
        }
    }
    const float bl = blin[w * 16 + l15];
    const float bg = bgate[w * 16 + l15];

    // ---- staging: thread covers rows {srow, srow+32}, 8-elem group skg
    const int srow = tid >> 4;         // 0..31
    const int skg  = tid & 15;
    f32x4 lv0, lv1, lv2, lv3;
    int   btn;
    auto stage_load = [&](int base) {
        const int nd0 = base + srow;
        const int nd1 = base + srow + 32;
        const float* p0 = x + (size_t)(nd0 < nN ? nd0 : nN - 1) * 128 + skg * 8;
        const float* p1 = x + (size_t)(nd1 < nN ? nd1 : nN - 1) * 128 + skg * 8;
        lv0 = *(const f32x4*)p0;
        lv1 = *(const f32x4*)(p0 + 4);
        lv2 = *(const f32x4*)p1;
        lv3 = *(const f32x4*)(p1 + 4);
        const int bi = base + lane;
        btn = (bi < nN) ? batch[bi] : -1;
    };
    auto stage_write = [&](int bsel) {   // counted vmcnt lands here
        const int b0 = (srow * 256 + skg * 16) ^ ((srow & 7) << 4);
        const int b1 = ((srow + 32) * 256 + skg * 16) ^ ((srow & 7) << 4);
        *(bf16x8*)((char*)&buf[bsel][0] + b0) = cvt8(lv0, lv1);
        *(bf16x8*)((char*)&buf[bsel][0] + b1) = cvt8(lv2, lv3);
    };

    float racc = 0.f;
    int   gcur = batch[R0];
    auto flush = [&](int g) {
        float v = racc;
        v += __shfl_xor(v, 16);
        v += __shfl_xor(v, 32);
        if (lg == 0) atomicAdd(sums + (size_t)g * 128 + w * 16 + l15, v);
        racc = 0.f;
    };

    // ---- prologue: tile 0 staged
    stage_load(R0);
    stage_write(0);
    int bt = btn;
    asm volatile("s_waitcnt lgkmcnt(0)\n\ts_barrier" ::: "memory");

    for (int t = 0; t < nt; ++t) {
        const int base = R0 + (t << 6);
        const bool more = (t + 1 < nt);
        if (more) stage_load(base + 64);   // loads in flight through GEMMs

        // ---- fused dual GEMM from bf16 LDS tile
        f32x4 accS[4], accG[4];
#pragma unroll
        for (int r16 = 0; r16 < 4; ++r16) { accS[r16] = (f32x4)0.f; accG[r16] = (f32x4)0.f; }
        const char* bc = (const char*)&buf[t & 1][0];
#pragma unroll
        for (int kk = 0; kk < 4; ++kk) {
#pragma unroll
            for (int r16 = 0; r16 < 4; ++r16) {
                const int row  = r16 * 16 + l15;
                const int byte = (row * 256 + kk * 64 + lg * 16) ^ ((l15 & 7) << 4);
                bf16x8 af = *(const bf16x8*)(bc + byte);
                accS[r16] = __builtin_amdgcn_mfma_f32_16x16x32_bf16(af, bfrag[0][kk], accS[r16], 0, 0, 0);
                accG[r16] = __builtin_amdgcn_mfma_f32_16x16x32_bf16(af, bfrag[1][kk], accG[r16], 0, 0, 0);
            }
        }

        // ---- exp + 16-lane row sums on the VALU (DPP ror 8/4/2/1)
#pragma unroll
        for (int r16 = 0; r16 < 4; ++r16) {
            f32x4 pv;
#pragma unroll
            for (int r = 0; r < 4; ++r) {
                float e = __expf(accG[r16][r] + bg);
                accG[r16][r] = e;
                float s = e;
                s = dpp_addf<0x128>(s);   // row_ror:8
                s = dpp_addf<0x124>(s);   // row_ror:4
                s = dpp_addf<0x122>(s);   // row_ror:2
                s = dpp_addf<0x121>(s);   // row_ror:1
                pv[r] = s;
            }
            if (l15 == 0) *(f32x4*)&PS[w][r16 * 16 + lg * 4] = pv;
        }

        if (more) stage_write((t + 1) & 1);   // write-late (T14), pre-B1
        asm volatile("s_waitcnt lgkmcnt(0)\n\ts_barrier" ::: "memory");  // B1

        // ---- stage 2: rows [8w,8w+8), 8 partials each
        {
            const int rw = w * 8 + (lane >> 3);
            float v = PS[lane & 7][rw];
            v = dpp_addf<0xB1>(v);    // quad_perm(1,0,3,2) == xor:1
            v = dpp_addf<0x4E>(v);    // quad_perm(2,3,0,1) == xor:2
            v = dpp_addf<0x141>(v);   // row_half_mirror -> completes 8-sum
            if ((lane & 7) == 0) invLds[rw] = 1.0f / v;
        }
        asm volatile("s_waitcnt lgkmcnt(0)\n\ts_barrier" ::: "memory");  // B2

        // ---- gating
#pragma unroll
        for (int r16 = 0; r16 < 4; ++r16) {
            f32x4 iv = *(const f32x4*)&invLds[r16 * 16 + lg * 4];
#pragma unroll
            for (int r = 0; r < 4; ++r)
                accS[r16][r] = (accS[r16][r] + bl) * accG[r16][r] * iv[r];
        }

        // ---- segmented per-graph accumulation (rows base..base+63, sorted)
        const int nvalid = min(64, nN - base);
        const int gf = __builtin_amdgcn_readlane(bt, 0);
        const int gl = __builtin_amdgcn_readlane(bt, nvalid - 1);
        if (nvalid == 64 && gf == gl) {
            if (gf != gcur) { flush(gcur); gcur = gf; }
            float ts = 0.f;
#pragma unroll
            for (int r16 = 0; r16 < 4; ++r16)
#pragma unroll
                for (int r = 0; r < 4; ++r) ts += accS[r16][r];
            racc += ts;
        } else {
            for (int g = gf; g <= gl; ++g) {
                float cs = 0.f;
#pragma unroll
                for (int r16 = 0; r16 < 4; ++r16)
#pragma unroll
                    for (int r = 0; r < 4; ++r) {
                        const int bid = __shfl(bt, r16 * 16 + lg * 4 + r);
                        cs += (bid == g) ? accS[r16][r] : 0.f;
                    }
                if (g == gcur) racc += cs;
                else { flush(gcur); gcur = g; racc = cs; }
            }
        }
        bt = btn;
    }
    flush(gcur);
}

// ---------------------------------------------------------------------------
// Kernel 2: mean = sums/count, out = mean @ Wf^T + bf
// ---------------------------------------------------------------------------
__global__ __launch_bounds__(128) void final_mm(
    const float* __restrict__ sums, const int* __restrict__ off,
    const float* __restrict__ Wf, const float* __restrict__ bf,
    float* __restrict__ out)
{
    const int g = blockIdx.x, c = threadIdx.x;
    __shared__ float m[128];
    const int cnt = off[g + 1] - off[g];
    const float invC = 1.0f / (float)(cnt > 0 ? cnt : 1);
    m[c] = sums[g * 128 + c] * invC;
    __syncthreads();
    float acc = bf[c];
    const f32x4* wr = (const f32x4*)(Wf + (size_t)c * 128);
#pragma unroll
    for (int k = 0; k < 32; ++k) {
        f32x4 wv = wr[k];
        acc += m[4 * k] * wv.x + m[4 * k + 1] * wv.y + m[4 * k + 2] * wv.z + m[4 * k + 3] * wv.w;
    }
    out[g * 128 + c] = acc;
}

extern "C" void kernel_launch(void* const* d_in, const int* in_sizes, int n_in,
                              void* d_out, int out_size, void* d_ws, size_t ws_size,
                              hipStream_t stream)
{
    const float* x     = (const float*)d_in[0];
    const int*   batch = (const int*)d_in[1];
    const float* Wlin  = (const float*)d_in[2];
    const float* blin  = (const float*)d_in[3];
    const float* Wgate = (const float*)d_in[4];
    const float* bgate = (const float*)d_in[5];
    const float* Wfin  = (const float*)d_in[6];
    const float* bfin  = (const float*)d_in[7];
    float* out  = (float*)d_out;
    float* sums = (float*)d_ws;                               // 512 KB
    int*   off  = (int*)((char*)d_ws + 512 * 1024);           // 1025 ints

    const int nNodes  = in_sizes[1];
    const int nGraphs = out_size / 128;

    // ~977 blocks, contiguous ranges, P multiple of 64
    const int P  = ((((nNodes + 1023) / 1024) + 63) & ~63);
    const int nB = (nNodes + P - 1) / P;

    prep<<<2048, 256, 0, stream>>>(batch, nNodes, sums, off);
    gnn_main<<<nB, 512, 0, stream>>>(x, batch, Wlin, blin, Wgate, bgate, sums, nNodes, P);
    final_mm<<<nGraphs, 128, 0, stream>>>(sums, off, Wfin, bfin, out);
}

// Round 13
// 84.731 us; speedup vs baseline: 1.1790x; 1.1790x over previous
//
#include <hip/hip_runtime.h>

typedef __attribute__((ext_vector_type(8))) __bf16 bf16x8;
typedef __attribute__((ext_vector_type(4))) float f32x4;

__device__ __forceinline__ bf16x8 cvt8(f32x4 a, f32x4 b) {
    bf16x8 v;
    v[0] = (__bf16)a.x; v[1] = (__bf16)a.y; v[2] = (__bf16)a.z; v[3] = (__bf16)a.w;
    v[4] = (__bf16)b.x; v[5] = (__bf16)b.y; v[6] = (__bf16)b.z; v[7] = (__bf16)b.w;
    return v;
}

// VALU-pipe cross-lane add via DPP (replaces ds_swizzle-based __shfl_xor)
template <int CTRL>
__device__ __forceinline__ float dpp_addf(float v) {
    union { float f; int i; } s, r;
    s.f = v;
    r.i = __builtin_amdgcn_update_dpp(0, s.i, CTRL, 0xF, 0xF, true);
    return v + r.f;
}

// ---------------------------------------------------------------------------
// Kernel 0: zero 512KB accumulator + build graph offsets from sorted batch.
// ---------------------------------------------------------------------------
__global__ void prep(const int* __restrict__ batch, int nN,
                     float* __restrict__ sums, int* __restrict__ off)
{
    const int i = blockIdx.x * blockDim.x + threadIdx.x;
    const int stride = gridDim.x * blockDim.x;
    for (int t = i; t < 1024 * 128; t += stride) sums[t] = 0.f;
    for (int t = i; t < nN; t += stride) {
        const int b  = batch[t];
        const int bp = (t == 0) ? -1 : batch[t - 1];
        for (int g = bp + 1; g <= b; ++g) off[g] = t;
        if (t == nN - 1) {
            for (int g = b + 1; g <= 1024; ++g) off[g] = nN;
        }
    }
}

// ---------------------------------------------------------------------------
// Kernel 1: R10 structure, bit-exact R10 arithmetic (512 thr / 8 waves,
// 32-row bf16 tiles, 2x8KB XOR-swizzled, DPP softmax, lgkm-only barriers,
// __expf gates, post-GEMM bias, scalar racc). ONE change vs R10: stage_load
// for tile t+2 is issued right after stage_write(t+1) frees the registers,
// giving a full-iteration prefetch gap (~1100cy > HBM ~900cy) so the counted
// vmcnt at the next stage_write never stalls.
// ---------------------------------------------------------------------------
__global__ __launch_bounds__(512, 2) void gnn_main(
    const float* __restrict__ x, const int* __restrict__ batch,
    const float* __restrict__ Wlin, const float* __restrict__ blin,
    const float* __restrict__ Wgate, const float* __restrict__ bgate,
    float* __restrict__ sums, int nN, int P)
{
    __shared__ __bf16 buf[2][32 * 128];   // 2 x 8 KB bf16, 16B-XOR swizzled
    __shared__ float  PS[8][36];          // per-wave row partial sums (padded)
    __shared__ float  invLds[32];         // per-row 1/sum

    const int tid  = threadIdx.x;
    const int lane = tid & 63;
    const int w    = tid >> 6;    // wave 0..7
    const int l15  = lane & 15;
    const int lg   = lane >> 4;   // 0..3

    const int R0 = blockIdx.x * P;
    if (R0 >= nN) return;
    const int R1b = min(R0 + P, nN);
    const int nt  = (R1b - R0 + 31) >> 5;

    // ---- W fragments (B operand): rows [16w,16w+16) of Wlin / Wgate
    bf16x8 bfrag[2][4];
    {
        const float* Wp0 = Wlin  + (size_t)(w * 16 + l15) * 128 + lg * 8;
        const float* Wp1 = Wgate + (size_t)(w * 16 + l15) * 128 + lg * 8;
#pragma unroll
        for (int kk = 0; kk < 4; ++kk) {
            bfrag[0][kk] = cvt8(*(const f32x4*)(Wp0 + kk * 32),
                                *(const f32x4*)(Wp0 + kk * 32 + 4));
            bfrag[1][kk] = cvt8(*(const f32x4*)(Wp1 + kk * 32),
                                *(const f32x4*)(Wp1 + kk * 32 + 4));
        }
    }
    const float bl = blin[w * 16 + l15];
    const float bg = bgate[w * 16 + l15];

    // ---- staging: thread covers x[base + (tid>>4)][(tid&15)*8 .. +7]
    const int srow = tid >> 4;         // 0..31
    const int skg  = tid & 15;         // 8-elem group
    f32x4 lv0, lv1;
    int   btn;
    auto stage_load = [&](int base) {
        const int nd = base + srow;
        const float* p = x + (size_t)(nd < nN ? nd : nN - 1) * 128 + skg * 8;
        lv0 = *(const f32x4*)p;
        lv1 = *(const f32x4*)(p + 4);
        const int bi = base + lane;
        btn = (bi < nN) ? batch[bi] : -1;
    };
    auto stage_write = [&](int bsel) {   // counted vmcnt lands here (~0 stall)
        const int byte = (srow * 256 + skg * 16) ^ ((srow & 7) << 4);
        *(bf16x8*)((char*)&buf[bsel][0] + byte) = cvt8(lv0, lv1);
    };

    float racc = 0.f;
    int   gcur = batch[R0];
    auto flush = [&](int g) {
        float v = racc;
        v += __shfl_xor(v, 16);
        v += __shfl_xor(v, 32);
        if (lg == 0) atomicAdd(sums + (size_t)g * 128 + w * 16 + l15, v);
        racc = 0.f;
    };

    // ---- prologue: tile 0 staged; tile 1 loads already in flight
    stage_load(R0);
    int bq0 = btn;                 // batch ids of tile t
    stage_write(0);
    if (nt > 1) stage_load(R0 + 32);
    int bq1 = btn;                 // batch ids of tile t+1
    asm volatile("s_waitcnt lgkmcnt(0)\n\ts_barrier" ::: "memory");

    for (int t = 0; t < nt; ++t) {
        const int base = R0 + (t << 5);

        // ---- fused dual GEMM from bf16 LDS tile (no cvt in hot loop)
        f32x4 accS[2], accG[2];
#pragma unroll
        for (int r16 = 0; r16 < 2; ++r16) { accS[r16] = (f32x4)0.f; accG[r16] = (f32x4)0.f; }
        const char* bc = (const char*)&buf[t & 1][0];
#pragma unroll
        for (int kk = 0; kk < 4; ++kk) {
#pragma unroll
            for (int r16 = 0; r16 < 2; ++r16) {
                const int row  = r16 * 16 + l15;
                const int byte = (row * 256 + kk * 64 + lg * 16) ^ ((l15 & 7) << 4);
                bf16x8 af = *(const bf16x8*)(bc + byte);
                accS[r16] = __builtin_amdgcn_mfma_f32_16x16x32_bf16(af, bfrag[0][kk], accS[r16], 0, 0, 0);
                accG[r16] = __builtin_amdgcn_mfma_f32_16x16x32_bf16(af, bfrag[1][kk], accG[r16], 0, 0, 0);
            }
        }

        // ---- exp + 16-lane row sums on the VALU (DPP ror 8/4/2/1)
#pragma unroll
        for (int r16 = 0; r16 < 2; ++r16) {
            f32x4 pv;
#pragma unroll
            for (int r = 0; r < 4; ++r) {
                float e = __expf(accG[r16][r] + bg);
                accG[r16][r] = e;
                float s = e;
                s = dpp_addf<0x128>(s);   // row_ror:8
                s = dpp_addf<0x124>(s);   // row_ror:4
                s = dpp_addf<0x122>(s);   // row_ror:2
                s = dpp_addf<0x121>(s);   // row_ror:1
                pv[r] = s;
            }
            if (l15 == 0) *(f32x4*)&PS[w][r16 * 16 + lg * 4] = pv;
        }

        if (t + 1 < nt) stage_write((t + 1) & 1);   // consume lv (vmcnt ~0)
        if (t + 2 < nt) stage_load(base + 64);      // re-issue, full iter ahead
        asm volatile("s_waitcnt lgkmcnt(0)\n\ts_barrier" ::: "memory");  // B1

        // ---- stage 2: rows [4w,4w+4), 8 partials each (x2 duplicated)
        {
            const int rw = w * 4 + (lane >> 4);
            float v = PS[lane & 7][rw];
            v = dpp_addf<0x124>(v);   // ror:4 == xor:4 under 8-dup
            v = dpp_addf<0x4E>(v);    // quad_perm(2,3,0,1) == xor:2
            v = dpp_addf<0xB1>(v);    // quad_perm(1,0,3,2) == xor:1
            if ((lane & 15) == 0) invLds[rw] = 1.0f / v;
        }
        asm volatile("s_waitcnt lgkmcnt(0)\n\ts_barrier" ::: "memory");  // B2

        // ---- gating
#pragma unroll
        for (int r16 = 0; r16 < 2; ++r16) {
            f32x4 iv = *(const f32x4*)&invLds[r16 * 16 + lg * 4];
#pragma unroll
            for (int r = 0; r < 4; ++r)
                accS[r16][r] = (accS[r16][r] + bl) * accG[r16][r] * iv[r];
        }

        // ---- segmented per-graph accumulation (rows base..base+31, sorted)
        const int bt = bq0;
        const int nvalid = min(32, nN - base);
        const int gf = __builtin_amdgcn_readlane(bt, 0);
        const int gl = __builtin_amdgcn_readlane(bt, nvalid - 1);
        if (nvalid == 32 && gf == gl) {
            if (gf != gcur) { flush(gcur); gcur = gf; }
            float ts = 0.f;
#pragma unroll
            for (int r16 = 0; r16 < 2; ++r16)
#pragma unroll
                for (int r = 0; r < 4; ++r) ts += accS[r16][r];
            racc += ts;
        } else {
            for (int g = gf; g <= gl; ++g) {
                float cs = 0.f;
#pragma unroll
                for (int r16 = 0; r16 < 2; ++r16)
#pragma unroll
                    for (int r = 0; r < 4; ++r) {
                        const int bid = __shfl(bt, r16 * 16 + lg * 4 + r);
                        cs += (bid == g) ? accS[r16][r] : 0.f;
                    }
                if (g == gcur) racc += cs;
                else { flush(gcur); gcur = g; racc = cs; }
            }
        }
        bq0 = bq1;
        bq1 = btn;
    }
    flush(gcur);
}

// ---------------------------------------------------------------------------
// Kernel 2: mean = sums/count, out = mean @ Wf^T + bf
// ---------------------------------------------------------------------------
__global__ __launch_bounds__(128) void final_mm(
    const float* __restrict__ sums, const int* __restrict__ off,
    const float* __restrict__ Wf, const float* __restrict__ bf,
    float* __restrict__ out)
{
    const int g = blockIdx.x, c = threadIdx.x;
    __shared__ float m[128];
    const int cnt = off[g + 1] - off[g];
    const float invC = 1.0f / (float)(cnt > 0 ? cnt : 1);
    m[c] = sums[g * 128 + c] * invC;
    __syncthreads();
    float acc = bf[c];
    const f32x4* wr = (const f32x4*)(Wf + (size_t)c * 128);
#pragma unroll
    for (int k = 0; k < 32; ++k) {
        f32x4 wv = wr[k];
        acc += m[4 * k] * wv.x + m[4 * k + 1] * wv.y + m[4 * k + 2] * wv.z + m[4 * k + 3] * wv.w;
    }
    out[g * 128 + c] = acc;
}

extern "C" void kernel_launch(void* const* d_in, const int* in_sizes, int n_in,
                              void* d_out, int out_size, void* d_ws, size_t ws_size,
                              hipStream_t stream)
{
    const float* x     = (const float*)d_in[0];
    const int*   batch = (const int*)d_in[1];
    const float* Wlin  = (const float*)d_in[2];
    const float* blin  = (const float*)d_in[3];
    const float* Wgate = (const float*)d_in[4];
    const float* bgate = (const float*)d_in[5];
    const float* Wfin  = (const float*)d_in[6];
    const float* bfin  = (const float*)d_in[7];
    float* out  = (float*)d_out;
    float* sums = (float*)d_ws;                               // 512 KB
    int*   off  = (int*)((char*)d_ws + 512 * 1024);           // 1025 ints

    const int nNodes  = in_sizes[1];
    const int nGraphs = out_size / 128;

    // ~977 blocks, contiguous ranges, P multiple of 32
    const int P  = ((((nNodes + 1023) / 1024) + 31) & ~31);
    const int nB = (nNodes + P - 1) / P;

    prep<<<1024, 256, 0, stream>>>(batch, nNodes, sums, off);
    gnn_main<<<nB, 512, 0, stream>>>(x, batch, Wlin, blin, Wgate, bgate, sums, nNodes, P);
    final_mm<<<nGraphs, 128, 0, stream>>>(sums, off, Wfin, bfin, out);
}